// Round 11
// baseline (241.371 us; speedup 1.0000x reference)
//
#include <hip/hip_runtime.h>
#include <math.h>

#define B 128
#define M 32
#define P 8732
#define C 21
#define ALPHA 10.0f
#define TILE 64          // priors per wave-tile in k2
#define PPB 512          // priors per block (4 waves x 2 tiles x 64)
#define NB2 18           // ceil(P / PPB)
#define CH 8             // k1 prior chunks
#define CS 1092          // ceil(P / CH)

// ---------------- k1a: per-chunk best prior per object (partials) -----------
__global__ __launch_bounds__(256) void k1_partial(
    const float* __restrict__ b_boxes, const float* __restrict__ priors,
    float* __restrict__ pI, float* __restrict__ pU, int* __restrict__ pidx,
    int* __restrict__ done) {
  if (blockIdx.x == 0 && threadIdx.x == 0) *done = 0;
  int b = blockIdx.x >> 3;
  int ch = blockIdx.x & 7;
  int wid = threadIdx.x >> 6;
  int lane = threadIdx.x & 63;
  int obase = wid * 8;

  float ox1[8], oy1[8], ox2[8], oy2[8], oarea[8], bI[8], bU[8];
  int bidx[8];
#pragma unroll
  for (int k = 0; k < 8; k++) {
    float4 bx = ((const float4*)b_boxes)[(size_t)b * M + obase + k];
    ox1[k] = bx.x; oy1[k] = bx.y; ox2[k] = bx.z; oy2[k] = bx.w;
    oarea[k] = (bx.z - bx.x) * (bx.w - bx.y);
    bI[k] = -1.0f; bU[k] = 1.0f; bidx[k] = P;
  }

  int pend = (ch + 1) * CS;
  if (pend > P) pend = P;
#pragma unroll 2
  for (int p = ch * CS + lane; p < pend; p += 64) {
    float4 pr = ((const float4*)priors)[p];
    float pw2 = pr.z * 0.5f, ph2 = pr.w * 0.5f;
    float px1 = pr.x - pw2, py1 = pr.y - ph2;
    float px2 = pr.x + pw2, py2 = pr.y + ph2;
    float areaP = pr.z * pr.w;
#pragma unroll
    for (int k = 0; k < 8; k++) {
      float iw = fminf(ox2[k], px2) - fmaxf(ox1[k], px1);
      float ih = fminf(oy2[k], py2) - fmaxf(oy1[k], py1);
      iw = fmaxf(iw, 0.0f);
      ih = fmaxf(ih, 0.0f);
      float inter = iw * ih;
      float uni = oarea[k] + areaP - inter;
      if (inter * bU[k] > bI[k] * uni) { bI[k] = inter; bU[k] = uni; bidx[k] = p; }
    }
  }
  for (int off = 32; off >= 1; off >>= 1) {
#pragma unroll
    for (int k = 0; k < 8; k++) {
      float oI = __shfl_xor(bI[k], off, 64);
      float oU = __shfl_xor(bU[k], off, 64);
      int oi = __shfl_xor(bidx[k], off, 64);
      float l = oI * bU[k], r = bI[k] * oU;
      if (l > r || (l == r && oi < bidx[k])) { bI[k] = oI; bU[k] = oU; bidx[k] = oi; }
    }
  }
  if (lane == 0) {
#pragma unroll
    for (int k = 0; k < 8; k++) {
      int idx = ((size_t)b * M + obase + k) * CH + ch;
      pI[idx] = bI[k]; pU[idx] = bU[k]; pidx[idx] = bidx[k];
    }
  }
}

// ---------------- k2: per-prior match + loc partial + CE --------------------
// v4: wave-private pipelined tiles. Each wave owns 2 tiles of 64 priors and a
// private LDS class buffer; while computing tile t from LDS it has tile t+1's
// coalesced loads in flight in registers. ZERO barriers in steady state (only
// the two startup barriers for boxes/sinv). Math identical to R10 (absmax 0).
__global__ __launch_bounds__(256) void k2_perprior(
    const float* __restrict__ pred_loc, const float* __restrict__ pred_cls,
    const float* __restrict__ b_boxes, const int* __restrict__ b_labels,
    const float* __restrict__ priors,
    const float* __restrict__ pI, const float* __restrict__ pU,
    const int* __restrict__ pidx,
    float* __restrict__ ploc, float* __restrict__ pce, int* __restrict__ pnp,
    float* __restrict__ confneg) {
  int b = blockIdx.y;
  int p0 = blockIdx.x * PPB;
  int tid = threadIdx.x;
  int wid = tid >> 6;
  int lane = tid & 63;

  __shared__ __align__(16) float sCls[4][TILE * C];  // 21504 B (wave-private)
  __shared__ __align__(16) float4 sbox[M];
  __shared__ float sarea[M];
  __shared__ int slab[M], sobj[M];
  __shared__ int sinv[PPB];                          // 2048 B

  sinv[tid] = 0x7fffffff;
  sinv[tid + 256] = 0x7fffffff;
  if (tid < M) {
    int m = tid;
    float4 bx = ((const float4*)b_boxes)[b * M + m];
    sbox[m] = bx;
    sarea[m] = (bx.z - bx.x) * (bx.w - bx.y);
    slab[m] = b_labels[b * M + m];
    // fused k1_reduce: fold 8 chunk partials for object m of image b
    int o = b * M + m;
    float cI = pI[o * CH], cU = pU[o * CH];
    int ci = pidx[o * CH];
#pragma unroll
    for (int ch = 1; ch < CH; ch++) {
      float nI = pI[o * CH + ch], nU = pU[o * CH + ch];
      int ni = pidx[o * CH + ch];
      if (nI * cU > cI * nU) { cI = nI; cU = nU; ci = ni; }
    }
    sobj[m] = ci;
  }
  __syncthreads();
  if (tid < M) {
    int t = sobj[tid] - p0;
    if (t >= 0 && t < PPB) atomicMin(&sinv[t], tid);
  }
  __syncthreads();  // last barrier — steady state below is wave-private

  float locpart = 0.0f, cepospart = 0.0f;
  int npos = 0;

  int tp0 = p0 + (wid * 2) * TILE;
  int tp1 = tp0 + TILE;

  float4 q[6];   // next tile's 64x21 classes, coalesced across lanes
  float4 prv;    // next tile's prior for this lane
  {
    int nv = P - tp0;
    nv = nv < 0 ? 0 : (nv > TILE ? TILE : nv);
    if (nv > 0) {
      int nf4 = (nv * C) >> 2;
      const float4* src = (const float4*)(pred_cls + ((size_t)b * P + tp0) * C);
#pragma unroll
      for (int k = 0; k < 6; k++) {
        int idx = lane + (k << 6);
        q[k] = src[idx < nf4 ? idx : 0];
      }
      prv = ((const float4*)priors)[tp0 + (lane < nv ? lane : 0)];
    }
  }

#pragma unroll
  for (int t = 0; t < 2; t++) {
    int ctp = (t == 0) ? tp0 : tp1;
    int nv = P - ctp;
    nv = nv < 0 ? 0 : (nv > TILE ? TILE : nv);
    if (nv == 0) break;
    int nf4 = (nv * C) >> 2;

    // stage regs -> private LDS (compiler inserts the vmcnt wait here)
    {
      float4* dst = (float4*)&sCls[wid][0];
#pragma unroll
      for (int k = 0; k < 6; k++) {
        int idx = lane + (k << 6);
        if (idx < nf4) dst[idx] = q[k];
      }
    }
    float4 myPr = prv;

    if (t == 0) {  // prefetch tile 1 while computing tile 0
      int nnv = P - tp1;
      nnv = nnv < 0 ? 0 : (nnv > TILE ? TILE : nnv);
      if (nnv > 0) {
        int nnf4 = (nnv * C) >> 2;
        const float4* src = (const float4*)(pred_cls + ((size_t)b * P + tp1) * C);
#pragma unroll
        for (int k = 0; k < 6; k++) {
          int idx = lane + (k << 6);
          q[k] = src[idx < nnf4 ? idx : 0];
        }
        prv = ((const float4*)priors)[tp1 + (lane < nnv ? lane : 0)];
      }
    }

    // ---- compute tile t ----
    bool act = lane < nv;
    int p = ctp + (act ? lane : 0);
    float pw2 = myPr.z * 0.5f, ph2 = myPr.w * 0.5f;
    float px1 = myPr.x - pw2, py1 = myPr.y - ph2;
    float px2 = myPr.x + pw2, py2 = myPr.y + ph2;
    float areaP = myPr.z * myPr.w;
    float bI = -1.0f, bU = 1.0f;
    int bm = 0;
    for (int m = 0; m < M; m++) {
      float4 bx = sbox[m];  // one ds_read_b128 broadcast per object
      float iw = fminf(bx.z, px2) - fmaxf(bx.x, px1);
      float ih = fminf(bx.w, py2) - fmaxf(bx.y, py1);
      iw = fmaxf(iw, 0.0f);
      ih = fmaxf(ih, 0.0f);
      float inter = iw * ih;
      float uni = sarea[m] + areaP - inter;
      if (inter * bU > bI * uni) { bI = inter; bU = uni; bm = m; }
    }
    int fm = sinv[ctp - p0 + lane];
    if (fm != 0x7fffffff) {
      if (!((bI == bU) && (bm < fm))) { bI = 1.0f; bU = 1.0f; bm = fm; }
    }
    bool pos = act && (2.0f * bI >= bU);  // iou >= 0.5, division-free
    int wAny = __any((int)pos);

    if (wAny) {  // wave-uniform positive path
      float4 pl = ((const float4*)pred_loc)[(size_t)b * P + p];
      float4 bx = sbox[bm];
      float cx = (bx.x + bx.z) * 0.5f, cy = (bx.y + bx.w) * 0.5f;
      float w = bx.z - bx.x, h = bx.w - bx.y;
      float rz = __builtin_amdgcn_rcpf(myPr.z);
      float rw = __builtin_amdgcn_rcpf(myPr.w);
      float g0 = (cx - myPr.x) * 10.0f * rz;
      float g1 = (cy - myPr.y) * 10.0f * rw;
      float g2 = __logf(w * rz) * 5.0f;
      float g3 = __logf(h * rw) * 5.0f;
      if (pos) {
        locpart += fabsf(pl.x - g0) + fabsf(pl.y - g1) +
                   fabsf(pl.z - g2) + fabsf(pl.w - g3);
        npos++;
      }
    }

    // CE from private LDS (unstabilized logsumexp; verified absmax 0.0)
    const float* u = &sCls[wid][lane * C];
    int cls = pos ? slab[bm] : 0;
    float se = 0.0f, vc = 0.0f;
#pragma unroll
    for (int c = 0; c < C; c++) {
      float x = u[c];
      se += __expf(x);
      if (c == cls) vc = x;  // predicated select, constant index
    }
    float ce = __logf(se) - vc;
    if (act) {
      confneg[(size_t)b * P + p] = pos ? 0.0f : ce;
      cepospart += pos ? ce : 0.0f;
    }
  }

  for (int off = 32; off >= 1; off >>= 1) {
    locpart += __shfl_down(locpart, off, 64);
    cepospart += __shfl_down(cepospart, off, 64);
    npos += __shfl_down(npos, off, 64);
  }
  __shared__ float rloc[4], rce[4];
  __shared__ int rnp[4];
  if (lane == 0) { rloc[wid] = locpart; rce[wid] = cepospart; rnp[wid] = npos; }
  __syncthreads();
  if (tid == 0) {
    int f = b * NB2 + blockIdx.x;
    ploc[f] = rloc[0] + rloc[1] + rloc[2] + rloc[3];
    pce[f] = rce[0] + rce[1] + rce[2] + rce[3];
    pnp[f] = rnp[0] + rnp[1] + rnp[2] + rnp[3];
  }
}

// ---------------- k3: per-image exact top-K + parallel finalize -------------
__global__ __launch_bounds__(1024) void k3_hardneg(
    const float* __restrict__ confneg,
    const float* __restrict__ ploc, const float* __restrict__ pce,
    const int* __restrict__ pnp,
    float* __restrict__ imgres, int* __restrict__ done,
    float* __restrict__ out) {
  int b = blockIdx.x;
  int tid = threadIdx.x;
  int wid = tid >> 6;
  int lane = tid & 63;

  __shared__ __align__(16) float s[P];
  __shared__ int histw[16 * 256];
  __shared__ __align__(16) int cnt[256];
  __shared__ int sdig, scum, sK, sLast;
  __shared__ float sLoc, sCe, sNp;
  __shared__ float rsum[16], rl[16], rc[16], rh[16], rn[16];
  __shared__ int rcnt[16];

  {
    const float4* row4 = (const float4*)(confneg + (size_t)b * P);
    for (int i = tid; i < P / 4; i += 1024) ((float4*)s)[i] = row4[i];
  }

  if (wid == 0) {  // wave 0: reduce this image's 18 per-block partials
    float lp = 0.0f, cp = 0.0f;
    int np = 0;
    if (lane < NB2) {
      int f = b * NB2 + lane;
      lp = ploc[f]; cp = pce[f]; np = pnp[f];
    }
    for (int off = 32; off >= 1; off >>= 1) {
      lp += __shfl_down(lp, off, 64);
      cp += __shfl_down(cp, off, 64);
      np += __shfl_down(np, off, 64);
    }
    if (lane == 0) {
      int K = np * 3;
      if (K > P) K = P;
      sK = K; sLoc = lp; sCe = cp; sNp = (float)np;
    }
  }
  __syncthreads();

  int K = sK;
  unsigned pfx = 0;
  int Krem = K;
#pragma unroll
  for (int pass = 3; pass >= 0; --pass) {
    int sh = pass * 8;
    for (int i = tid; i < 16 * 256; i += 1024) histw[i] = 0;
    __syncthreads();
    unsigned himask = (pass == 3) ? 0u : (0xFFFFFFFFu << (sh + 8));
    int* myh = &histw[wid * 256];
    for (int i = tid; i < P; i += 1024) {
      unsigned ub = __float_as_uint(s[i]);
      if ((ub & himask) == pfx) atomicAdd(&myh[(ub >> sh) & 255], 1);
    }
    __syncthreads();
    if (tid < 256) {
      int c = 0;
#pragma unroll
      for (int w = 0; w < 16; w++) c += histw[w * 256 + tid];
      cnt[tid] = c;
    }
    __syncthreads();
    if (wid == 0) {
      int4 c4 = ((const int4*)cnt)[lane];
      int s3 = c4.w;
      int s2 = c4.z + s3;
      int s1 = c4.y + s2;
      int s0 = c4.x + s1;
      int suf = s0;
      for (int off = 1; off < 64; off <<= 1) {
        int t = __shfl_down(suf, off, 64);
        if (lane + off < 64) suf += t;
      }
      int above = suf - s0;
      int S0 = above + s0, S1 = above + s1, S2 = above + s2, S3 = above + s3;
      int S4 = above;
      if (S3 >= Krem && S4 < Krem) { sdig = 4 * lane + 3; scum = S4; }
      else if (S2 >= Krem && S3 < Krem) { sdig = 4 * lane + 2; scum = S3; }
      else if (S1 >= Krem && S2 < Krem) { sdig = 4 * lane + 1; scum = S2; }
      else if (S0 >= Krem && S1 < Krem) { sdig = 4 * lane + 0; scum = S1; }
    }
    __syncthreads();
    pfx |= ((unsigned)sdig) << sh;
    Krem -= scum;
  }
  float tau = __uint_as_float(pfx);

  float sum = 0.0f;
  int cgt = 0;
  for (int i = tid; i < P; i += 1024) {
    float v = s[i];
    if (v > tau) { sum += v; cgt++; }
  }
  for (int off = 32; off >= 1; off >>= 1) {
    sum += __shfl_down(sum, off, 64);
    cgt += __shfl_down(cgt, off, 64);
  }
  if (lane == 0) { rsum[wid] = sum; rcnt[wid] = cgt; }
  __syncthreads();
  if (tid == 0) {
    float stot = 0.0f;
    int ctot = 0;
#pragma unroll
    for (int w = 0; w < 16; w++) { stot += rsum[w]; ctot += rcnt[w]; }
    float hard = stot + (float)(K - ctot) * tau;
    imgres[b * 4 + 0] = sLoc;
    imgres[b * 4 + 1] = sCe;
    imgres[b * 4 + 2] = hard;
    imgres[b * 4 + 3] = sNp;
    __threadfence();
    int prev = atomicAdd(done, 1);
    sLast = (prev == B - 1) ? 1 : 0;
  }
  __syncthreads();
  if (sLast) {
    __threadfence();
    float l = 0.0f, c = 0.0f, h = 0.0f, n = 0.0f;
    if (tid < B) {
      l = atomicAdd(&imgres[tid * 4 + 0], 0.0f);
      c = atomicAdd(&imgres[tid * 4 + 1], 0.0f);
      h = atomicAdd(&imgres[tid * 4 + 2], 0.0f);
      n = atomicAdd(&imgres[tid * 4 + 3], 0.0f);
    }
    for (int off = 32; off >= 1; off >>= 1) {
      l += __shfl_down(l, off, 64);
      c += __shfl_down(c, off, 64);
      h += __shfl_down(h, off, 64);
      n += __shfl_down(n, off, 64);
    }
    if (lane == 0) { rl[wid] = l; rc[wid] = c; rh[wid] = h; rn[wid] = n; }
    __syncthreads();
    if (tid == 0) {
      float L = 0, Cc = 0, H = 0, N = 0;
#pragma unroll
      for (int w = 0; w < 16; w++) { L += rl[w]; Cc += rc[w]; H += rh[w]; N += rn[w]; }
      float loc = ALPHA * L / (N * 4.0f);
      float conf = (H + Cc) / N;
      out[0] = conf + loc;
      out[1] = loc;
      out[2] = conf;
    }
  }
}

extern "C" void kernel_launch(void* const* d_in, const int* in_sizes, int n_in,
                              void* d_out, int out_size, void* d_ws, size_t ws_size,
                              hipStream_t stream) {
  (void)in_sizes; (void)n_in; (void)out_size; (void)ws_size;
  const float* pred_loc = (const float*)d_in[0];
  const float* pred_cls = (const float*)d_in[1];
  const float* b_boxes = (const float*)d_in[2];
  const int* b_labels = (const int*)d_in[3];
  const float* priors = (const float*)d_in[4];
  float* out = (float*)d_out;

  int* done = (int*)d_ws;
  float* ploc = (float*)d_ws + 8;
  float* pce = ploc + B * NB2;
  int* pnp = (int*)(pce + B * NB2);
  float* imgres = (float*)(pnp + B * NB2);
  float* pI = imgres + B * 4;
  float* pU = pI + B * M * CH;
  int* pidx = (int*)(pU + B * M * CH);
  float* confneg = (float*)(pidx + B * M * CH);

  k1_partial<<<B * CH, 256, 0, stream>>>(b_boxes, priors, pI, pU, pidx, done);
  dim3 g2(NB2, B);
  k2_perprior<<<g2, 256, 0, stream>>>(pred_loc, pred_cls, b_boxes, b_labels,
                                      priors, pI, pU, pidx,
                                      ploc, pce, pnp, confneg);
  k3_hardneg<<<B, 1024, 0, stream>>>(confneg, ploc, pce, pnp, imgres, done, out);
}

// Round 12
// 235.629 us; speedup vs baseline: 1.0244x; 1.0244x over previous
//
#include <hip/hip_runtime.h>
#include <math.h>

#define B 128
#define M 32
#define P 8732
#define C 21
#define ALPHA 10.0f
#define PPB 256          // priors per k2 block (2 waves x 128)
#define NB2 35           // ceil(P / PPB)
#define CH 8             // k1 prior chunks
#define CS 1092          // ceil(P / CH)

// ---------------- k1a: per-chunk best prior per object (partials) -----------
__global__ __launch_bounds__(256) void k1_partial(
    const float* __restrict__ b_boxes, const float* __restrict__ priors,
    float* __restrict__ pI, float* __restrict__ pU, int* __restrict__ pidx,
    int* __restrict__ done) {
  if (blockIdx.x == 0 && threadIdx.x == 0) *done = 0;
  int b = blockIdx.x >> 3;
  int ch = blockIdx.x & 7;
  int wid = threadIdx.x >> 6;
  int lane = threadIdx.x & 63;
  int obase = wid * 8;

  float ox1[8], oy1[8], ox2[8], oy2[8], oarea[8], bI[8], bU[8];
  int bidx[8];
#pragma unroll
  for (int k = 0; k < 8; k++) {
    float4 bx = ((const float4*)b_boxes)[(size_t)b * M + obase + k];
    ox1[k] = bx.x; oy1[k] = bx.y; ox2[k] = bx.z; oy2[k] = bx.w;
    oarea[k] = (bx.z - bx.x) * (bx.w - bx.y);
    bI[k] = -1.0f; bU[k] = 1.0f; bidx[k] = P;
  }

  int pend = (ch + 1) * CS;
  if (pend > P) pend = P;
#pragma unroll 2
  for (int p = ch * CS + lane; p < pend; p += 64) {
    float4 pr = ((const float4*)priors)[p];
    float pw2 = pr.z * 0.5f, ph2 = pr.w * 0.5f;
    float px1 = pr.x - pw2, py1 = pr.y - ph2;
    float px2 = pr.x + pw2, py2 = pr.y + ph2;
    float areaP = pr.z * pr.w;
#pragma unroll
    for (int k = 0; k < 8; k++) {
      float iw = fminf(ox2[k], px2) - fmaxf(ox1[k], px1);
      float ih = fminf(oy2[k], py2) - fmaxf(oy1[k], py1);
      iw = fmaxf(iw, 0.0f);
      ih = fmaxf(ih, 0.0f);
      float inter = iw * ih;
      float uni = oarea[k] + areaP - inter;
      if (inter * bU[k] > bI[k] * uni) { bI[k] = inter; bU[k] = uni; bidx[k] = p; }
    }
  }
  for (int off = 32; off >= 1; off >>= 1) {
#pragma unroll
    for (int k = 0; k < 8; k++) {
      float oI = __shfl_xor(bI[k], off, 64);
      float oU = __shfl_xor(bU[k], off, 64);
      int oi = __shfl_xor(bidx[k], off, 64);
      float l = oI * bU[k], r = bI[k] * oU;
      if (l > r || (l == r && oi < bidx[k])) { bI[k] = oI; bU[k] = oU; bidx[k] = oi; }
    }
  }
  if (lane == 0) {
#pragma unroll
    for (int k = 0; k < 8; k++) {
      int idx = ((size_t)b * M + obase + k) * CH + ch;
      pI[idx] = bI[k]; pU[idx] = bU[k]; pidx[idx] = bidx[k];
    }
  }
}

// ---------------- k2: per-prior match + loc partial + CE --------------------
// v5: R10 structure, but 2 priors per lane (128 priors/wave, 2-wave blocks).
// Each sbox/sarea LDS broadcast in the match loop now serves 2 priors; all
// per-wave fixed costs amortize 2x. No register prefetch arrays (no spill).
// Math identical to R10 (absmax 0.0).
__global__ __launch_bounds__(128) void k2_perprior(
    const float* __restrict__ pred_loc, const float* __restrict__ pred_cls,
    const float* __restrict__ b_boxes, const int* __restrict__ b_labels,
    const float* __restrict__ priors,
    const float* __restrict__ pI, const float* __restrict__ pU,
    const int* __restrict__ pidx,
    float* __restrict__ ploc, float* __restrict__ pce, int* __restrict__ pnp,
    float* __restrict__ confneg) {
  int b = blockIdx.y;
  int p0 = blockIdx.x * PPB;
  int tid = threadIdx.x;
  int wid = tid >> 6;
  int lane = tid & 63;

  __shared__ __align__(16) float sCls[2][128 * C];  // 21504 B
  __shared__ __align__(16) float4 sbox[M];
  __shared__ float sarea[M];
  __shared__ int slab[M], sobj[M];
  __shared__ int sinv[PPB];

  sinv[tid] = 0x7fffffff;
  sinv[tid + 128] = 0x7fffffff;
  if (tid < M) {
    int m = tid;
    float4 bx = ((const float4*)b_boxes)[b * M + m];
    sbox[m] = bx;
    sarea[m] = (bx.z - bx.x) * (bx.w - bx.y);
    slab[m] = b_labels[b * M + m];
    // fused k1_reduce: fold 8 chunk partials for object m of image b
    int o = b * M + m;
    float cI = pI[o * CH], cU = pU[o * CH];
    int ci = pidx[o * CH];
#pragma unroll
    for (int ch = 1; ch < CH; ch++) {
      float nI = pI[o * CH + ch], nU = pU[o * CH + ch];
      int ni = pidx[o * CH + ch];
      if (nI * cU > cI * nU) { cI = nI; cU = nU; ci = ni; }
    }
    sobj[m] = ci;
  }
  __syncthreads();
  if (tid < M) {
    int t = sobj[tid] - p0;
    if (t >= 0 && t < PPB) atomicMin(&sinv[t], tid);
  }
  // wave-private coalesced staging: this wave's 128 priors x 21 classes
  int wp0 = p0 + wid * 128;
  int nv = P - wp0;
  nv = nv < 0 ? 0 : (nv > 128 ? 128 : nv);
  {
    int nf4 = (nv * C) >> 2;  // nv in {128, 28, 0} -> nv*21 divisible by 4
    const float4* src = (const float4*)(pred_cls + ((size_t)b * P + wp0) * C);
    float4* dst = (float4*)&sCls[wid][0];
    for (int i = lane; i < nf4; i += 64) dst[i] = src[i];
  }
  __syncthreads();

  float locpart = 0.0f, cepospart = 0.0f;
  int npos = 0;
  if (nv > 0) {
    bool actA = lane < (nv < 64 ? nv : 64);
    bool actB = (64 + lane) < nv;
    int pA = wp0 + (actA ? lane : 0);
    int pB = wp0 + (actB ? 64 + lane : 0);
    float4 prA = ((const float4*)priors)[pA];
    float4 prB = ((const float4*)priors)[pB];

    float aw2 = prA.z * 0.5f, ah2 = prA.w * 0.5f;
    float ax1 = prA.x - aw2, ay1 = prA.y - ah2;
    float ax2 = prA.x + aw2, ay2 = prA.y + ah2;
    float areaA = prA.z * prA.w;
    float bw2 = prB.z * 0.5f, bh2 = prB.w * 0.5f;
    float bx1p = prB.x - bw2, by1p = prB.y - bh2;
    float bx2p = prB.x + bw2, by2p = prB.y + bh2;
    float areaB = prB.z * prB.w;

    float aI = -1.0f, aU = 1.0f, bI = -1.0f, bU = 1.0f;
    int am = 0, bmm = 0;
    for (int m = 0; m < M; m++) {
      float4 bx = sbox[m];   // one b128 broadcast serves both priors
      float ar = sarea[m];
      {
        float iw = fminf(bx.z, ax2) - fmaxf(bx.x, ax1);
        float ih = fminf(bx.w, ay2) - fmaxf(bx.y, ay1);
        iw = fmaxf(iw, 0.0f);
        ih = fmaxf(ih, 0.0f);
        float inter = iw * ih;
        float uni = ar + areaA - inter;
        if (inter * aU > aI * uni) { aI = inter; aU = uni; am = m; }
      }
      {
        float iw = fminf(bx.z, bx2p) - fmaxf(bx.x, bx1p);
        float ih = fminf(bx.w, by2p) - fmaxf(bx.y, by1p);
        iw = fmaxf(iw, 0.0f);
        ih = fmaxf(ih, 0.0f);
        float inter = iw * ih;
        float uni = ar + areaB - inter;
        if (inter * bU > bI * uni) { bI = inter; bU = uni; bmm = m; }
      }
    }
    // forced best-prior override (first-max semantics preserved, as R10)
    {
      int fm = sinv[wp0 - p0 + lane];
      if (fm != 0x7fffffff) {
        if (!((aI == aU) && (am < fm))) { aI = 1.0f; aU = 1.0f; am = fm; }
      }
      int fm2 = sinv[wp0 - p0 + 64 + lane];
      if (fm2 != 0x7fffffff) {
        if (!((bI == bU) && (bmm < fm2))) { bI = 1.0f; bU = 1.0f; bmm = fm2; }
      }
    }
    bool posA = actA && (2.0f * aI >= aU);
    bool posB = actB && (2.0f * bI >= bU);
    int wAny = __any((int)(posA | posB));

    if (wAny) {  // wave-uniform positive path: loc loads + encode + L1 loss
      float4 plA = ((const float4*)pred_loc)[(size_t)b * P + pA];
      float4 plB = ((const float4*)pred_loc)[(size_t)b * P + pB];
      {
        float4 bx = sbox[am];
        float cx = (bx.x + bx.z) * 0.5f, cy = (bx.y + bx.w) * 0.5f;
        float w = bx.z - bx.x, h = bx.w - bx.y;
        float rz = __builtin_amdgcn_rcpf(prA.z);
        float rw = __builtin_amdgcn_rcpf(prA.w);
        float g0 = (cx - prA.x) * 10.0f * rz;
        float g1 = (cy - prA.y) * 10.0f * rw;
        float g2 = __logf(w * rz) * 5.0f;
        float g3 = __logf(h * rw) * 5.0f;
        if (posA) {
          locpart += fabsf(plA.x - g0) + fabsf(plA.y - g1) +
                     fabsf(plA.z - g2) + fabsf(plA.w - g3);
          npos++;
        }
      }
      {
        float4 bx = sbox[bmm];
        float cx = (bx.x + bx.z) * 0.5f, cy = (bx.y + bx.w) * 0.5f;
        float w = bx.z - bx.x, h = bx.w - bx.y;
        float rz = __builtin_amdgcn_rcpf(prB.z);
        float rw = __builtin_amdgcn_rcpf(prB.w);
        float g0 = (cx - prB.x) * 10.0f * rz;
        float g1 = (cy - prB.y) * 10.0f * rw;
        float g2 = __logf(w * rz) * 5.0f;
        float g3 = __logf(h * rw) * 5.0f;
        if (posB) {
          locpart += fabsf(plB.x - g0) + fabsf(plB.y - g1) +
                     fabsf(plB.z - g2) + fabsf(plB.w - g3);
          npos++;
        }
      }
    }

    // CE from LDS (unstabilized logsumexp; verified absmax 0.0 since R9)
    {
      const float* u = &sCls[wid][lane * C];
      int cls = posA ? slab[am] : 0;
      float se = 0.0f, vc = 0.0f;
#pragma unroll
      for (int c = 0; c < C; c++) {
        float x = u[c];
        se += __expf(x);
        if (c == cls) vc = x;
      }
      float ce = __logf(se) - vc;
      if (actA) {
        confneg[(size_t)b * P + pA] = posA ? 0.0f : ce;
        cepospart += posA ? ce : 0.0f;
      }
    }
    {
      const float* u = &sCls[wid][(64 + lane) * C];
      int cls = posB ? slab[bmm] : 0;
      float se = 0.0f, vc = 0.0f;
#pragma unroll
      for (int c = 0; c < C; c++) {
        float x = u[c];
        se += __expf(x);
        if (c == cls) vc = x;
      }
      float ce = __logf(se) - vc;
      if (actB) {
        confneg[(size_t)b * P + pB] = posB ? 0.0f : ce;
        cepospart += posB ? ce : 0.0f;
      }
    }
  }

  for (int off = 32; off >= 1; off >>= 1) {
    locpart += __shfl_down(locpart, off, 64);
    cepospart += __shfl_down(cepospart, off, 64);
    npos += __shfl_down(npos, off, 64);
  }
  __shared__ float rloc[2], rce[2];
  __shared__ int rnp[2];
  if (lane == 0) { rloc[wid] = locpart; rce[wid] = cepospart; rnp[wid] = npos; }
  __syncthreads();
  if (tid == 0) {
    int f = b * NB2 + blockIdx.x;
    ploc[f] = rloc[0] + rloc[1];
    pce[f] = rce[0] + rce[1];
    pnp[f] = rnp[0] + rnp[1];
  }
}

// ---------------- k3: per-image exact top-K + parallel finalize -------------
__global__ __launch_bounds__(1024) void k3_hardneg(
    const float* __restrict__ confneg,
    const float* __restrict__ ploc, const float* __restrict__ pce,
    const int* __restrict__ pnp,
    float* __restrict__ imgres, int* __restrict__ done,
    float* __restrict__ out) {
  int b = blockIdx.x;
  int tid = threadIdx.x;
  int wid = tid >> 6;
  int lane = tid & 63;

  __shared__ __align__(16) float s[P];
  __shared__ int histw[16 * 256];
  __shared__ __align__(16) int cnt[256];
  __shared__ int sdig, scum, sK, sLast;
  __shared__ float sLoc, sCe, sNp;
  __shared__ float rsum[16], rl[16], rc[16], rh[16], rn[16];
  __shared__ int rcnt[16];

  {
    const float4* row4 = (const float4*)(confneg + (size_t)b * P);
    for (int i = tid; i < P / 4; i += 1024) ((float4*)s)[i] = row4[i];
  }

  if (wid == 0) {  // wave 0: reduce this image's 35 per-block partials
    float lp = 0.0f, cp = 0.0f;
    int np = 0;
    if (lane < NB2) {
      int f = b * NB2 + lane;
      lp = ploc[f]; cp = pce[f]; np = pnp[f];
    }
    for (int off = 32; off >= 1; off >>= 1) {
      lp += __shfl_down(lp, off, 64);
      cp += __shfl_down(cp, off, 64);
      np += __shfl_down(np, off, 64);
    }
    if (lane == 0) {
      int K = np * 3;
      if (K > P) K = P;
      sK = K; sLoc = lp; sCe = cp; sNp = (float)np;
    }
  }
  __syncthreads();

  int K = sK;
  unsigned pfx = 0;
  int Krem = K;
#pragma unroll
  for (int pass = 3; pass >= 0; --pass) {
    int sh = pass * 8;
    for (int i = tid; i < 16 * 256; i += 1024) histw[i] = 0;
    __syncthreads();
    unsigned himask = (pass == 3) ? 0u : (0xFFFFFFFFu << (sh + 8));
    int* myh = &histw[wid * 256];
    for (int i = tid; i < P; i += 1024) {
      unsigned ub = __float_as_uint(s[i]);
      if ((ub & himask) == pfx) atomicAdd(&myh[(ub >> sh) & 255], 1);
    }
    __syncthreads();
    if (tid < 256) {
      int c = 0;
#pragma unroll
      for (int w = 0; w < 16; w++) c += histw[w * 256 + tid];
      cnt[tid] = c;
    }
    __syncthreads();
    if (wid == 0) {
      int4 c4 = ((const int4*)cnt)[lane];
      int s3 = c4.w;
      int s2 = c4.z + s3;
      int s1 = c4.y + s2;
      int s0 = c4.x + s1;
      int suf = s0;
      for (int off = 1; off < 64; off <<= 1) {
        int t = __shfl_down(suf, off, 64);
        if (lane + off < 64) suf += t;
      }
      int above = suf - s0;
      int S0 = above + s0, S1 = above + s1, S2 = above + s2, S3 = above + s3;
      int S4 = above;
      if (S3 >= Krem && S4 < Krem) { sdig = 4 * lane + 3; scum = S4; }
      else if (S2 >= Krem && S3 < Krem) { sdig = 4 * lane + 2; scum = S3; }
      else if (S1 >= Krem && S2 < Krem) { sdig = 4 * lane + 1; scum = S2; }
      else if (S0 >= Krem && S1 < Krem) { sdig = 4 * lane + 0; scum = S1; }
    }
    __syncthreads();
    pfx |= ((unsigned)sdig) << sh;
    Krem -= scum;
  }
  float tau = __uint_as_float(pfx);

  float sum = 0.0f;
  int cgt = 0;
  for (int i = tid; i < P; i += 1024) {
    float v = s[i];
    if (v > tau) { sum += v; cgt++; }
  }
  for (int off = 32; off >= 1; off >>= 1) {
    sum += __shfl_down(sum, off, 64);
    cgt += __shfl_down(cgt, off, 64);
  }
  if (lane == 0) { rsum[wid] = sum; rcnt[wid] = cgt; }
  __syncthreads();
  if (tid == 0) {
    float stot = 0.0f;
    int ctot = 0;
#pragma unroll
    for (int w = 0; w < 16; w++) { stot += rsum[w]; ctot += rcnt[w]; }
    float hard = stot + (float)(K - ctot) * tau;
    imgres[b * 4 + 0] = sLoc;
    imgres[b * 4 + 1] = sCe;
    imgres[b * 4 + 2] = hard;
    imgres[b * 4 + 3] = sNp;
    __threadfence();
    int prev = atomicAdd(done, 1);
    sLast = (prev == B - 1) ? 1 : 0;
  }
  __syncthreads();
  if (sLast) {
    __threadfence();
    float l = 0.0f, c = 0.0f, h = 0.0f, n = 0.0f;
    if (tid < B) {
      l = atomicAdd(&imgres[tid * 4 + 0], 0.0f);
      c = atomicAdd(&imgres[tid * 4 + 1], 0.0f);
      h = atomicAdd(&imgres[tid * 4 + 2], 0.0f);
      n = atomicAdd(&imgres[tid * 4 + 3], 0.0f);
    }
    for (int off = 32; off >= 1; off >>= 1) {
      l += __shfl_down(l, off, 64);
      c += __shfl_down(c, off, 64);
      h += __shfl_down(h, off, 64);
      n += __shfl_down(n, off, 64);
    }
    if (lane == 0) { rl[wid] = l; rc[wid] = c; rh[wid] = h; rn[wid] = n; }
    __syncthreads();
    if (tid == 0) {
      float L = 0, Cc = 0, H = 0, N = 0;
#pragma unroll
      for (int w = 0; w < 16; w++) { L += rl[w]; Cc += rc[w]; H += rh[w]; N += rn[w]; }
      float loc = ALPHA * L / (N * 4.0f);
      float conf = (H + Cc) / N;
      out[0] = conf + loc;
      out[1] = loc;
      out[2] = conf;
    }
  }
}

extern "C" void kernel_launch(void* const* d_in, const int* in_sizes, int n_in,
                              void* d_out, int out_size, void* d_ws, size_t ws_size,
                              hipStream_t stream) {
  (void)in_sizes; (void)n_in; (void)out_size; (void)ws_size;
  const float* pred_loc = (const float*)d_in[0];
  const float* pred_cls = (const float*)d_in[1];
  const float* b_boxes = (const float*)d_in[2];
  const int* b_labels = (const int*)d_in[3];
  const float* priors = (const float*)d_in[4];
  float* out = (float*)d_out;

  int* done = (int*)d_ws;
  float* ploc = (float*)d_ws + 8;
  float* pce = ploc + B * NB2;
  int* pnp = (int*)(pce + B * NB2);
  float* imgres = (float*)(pnp + B * NB2);
  float* pI = imgres + B * 4;
  float* pU = pI + B * M * CH;
  int* pidx = (int*)(pU + B * M * CH);
  float* confneg = (float*)(pidx + B * M * CH);

  k1_partial<<<B * CH, 256, 0, stream>>>(b_boxes, priors, pI, pU, pidx, done);
  dim3 g2(NB2, B);
  k2_perprior<<<g2, 128, 0, stream>>>(pred_loc, pred_cls, b_boxes, b_labels,
                                      priors, pI, pU, pidx,
                                      ploc, pce, pnp, confneg);
  k3_hardneg<<<B, 1024, 0, stream>>>(confneg, ploc, pce, pnp, imgres, done, out);
}

// Round 13
// 214.175 us; speedup vs baseline: 1.1270x; 1.1002x over previous
//
#include <hip/hip_runtime.h>
#include <math.h>

#define B 128
#define M 32
#define P 8732
#define C 21
#define ALPHA 10.0f
#define TPB2 256
#define PPB 256          // priors per block in k2 (1 per lane, 64 per wave)
#define NB2 35           // ceil(P / PPB)
#define CH 8             // k1 prior chunks
#define CS 1092          // ceil(P / CH)

// direct global->LDS DMA, 16 B/lane, wave-uniform LDS base + lane*16 scatter
#define GLD16(g, l)                                                   \
  __builtin_amdgcn_global_load_lds(                                   \
      (__attribute__((address_space(1))) void*)(g),                   \
      (__attribute__((address_space(3))) void*)(l), 16, 0, 0)

// ---------------- k1a: per-chunk best prior per object (partials) -----------
__global__ __launch_bounds__(256) void k1_partial(
    const float* __restrict__ b_boxes, const float* __restrict__ priors,
    float* __restrict__ pI, float* __restrict__ pU, int* __restrict__ pidx,
    int* __restrict__ done) {
  if (blockIdx.x == 0 && threadIdx.x == 0) *done = 0;
  int b = blockIdx.x >> 3;
  int ch = blockIdx.x & 7;
  int wid = threadIdx.x >> 6;
  int lane = threadIdx.x & 63;
  int obase = wid * 8;

  float ox1[8], oy1[8], ox2[8], oy2[8], oarea[8], bI[8], bU[8];
  int bidx[8];
#pragma unroll
  for (int k = 0; k < 8; k++) {
    float4 bx = ((const float4*)b_boxes)[(size_t)b * M + obase + k];
    ox1[k] = bx.x; oy1[k] = bx.y; ox2[k] = bx.z; oy2[k] = bx.w;
    oarea[k] = (bx.z - bx.x) * (bx.w - bx.y);
    bI[k] = -1.0f; bU[k] = 1.0f; bidx[k] = P;
  }

  int pend = (ch + 1) * CS;
  if (pend > P) pend = P;
#pragma unroll 2
  for (int p = ch * CS + lane; p < pend; p += 64) {
    float4 pr = ((const float4*)priors)[p];
    float pw2 = pr.z * 0.5f, ph2 = pr.w * 0.5f;
    float px1 = pr.x - pw2, py1 = pr.y - ph2;
    float px2 = pr.x + pw2, py2 = pr.y + ph2;
    float areaP = pr.z * pr.w;
#pragma unroll
    for (int k = 0; k < 8; k++) {
      float iw = fminf(ox2[k], px2) - fmaxf(ox1[k], px1);
      float ih = fminf(oy2[k], py2) - fmaxf(oy1[k], py1);
      iw = fmaxf(iw, 0.0f);
      ih = fmaxf(ih, 0.0f);
      float inter = iw * ih;
      float uni = oarea[k] + areaP - inter;
      if (inter * bU[k] > bI[k] * uni) { bI[k] = inter; bU[k] = uni; bidx[k] = p; }
    }
  }
  for (int off = 32; off >= 1; off >>= 1) {
#pragma unroll
    for (int k = 0; k < 8; k++) {
      float oI = __shfl_xor(bI[k], off, 64);
      float oU = __shfl_xor(bU[k], off, 64);
      int oi = __shfl_xor(bidx[k], off, 64);
      float l = oI * bU[k], r = bI[k] * oU;
      if (l > r || (l == r && oi < bidx[k])) { bI[k] = oI; bU[k] = oU; bidx[k] = oi; }
    }
  }
  if (lane == 0) {
#pragma unroll
    for (int k = 0; k < 8; k++) {
      int idx = ((size_t)b * M + obase + k) * CH + ch;
      pI[idx] = bI[k]; pU[idx] = bU[k]; pidx[idx] = bidx[k];
    }
  }
}

// ---------------- k2: per-prior match + loc partial + CE --------------------
// v6 = R10 structure (best known: 1 prior/lane, 4-wave blocks, wave-private
// LDS class tile) with the staging round-trip replaced by
// global_load_lds width=16 (no VGPR round-trip, no ds_write).
__global__ __launch_bounds__(TPB2) void k2_perprior(
    const float* __restrict__ pred_loc, const float* __restrict__ pred_cls,
    const float* __restrict__ b_boxes, const int* __restrict__ b_labels,
    const float* __restrict__ priors,
    const float* __restrict__ pI, const float* __restrict__ pU,
    const int* __restrict__ pidx,
    float* __restrict__ ploc, float* __restrict__ pce, int* __restrict__ pnp,
    float* __restrict__ confneg) {
  int b = blockIdx.y;
  int p0 = blockIdx.x * PPB;
  int tid = threadIdx.x;
  int wid = tid >> 6;
  int lane = tid & 63;

  __shared__ __align__(16) float sCls[4][64 * C];  // 21504 B (wave-private)
  __shared__ __align__(16) float4 sbox[M];
  __shared__ float sarea[M];
  __shared__ int slab[M], sobj[M];
  __shared__ int sinv[PPB];

  // issue the DMA staging FIRST so it overlaps the setup work below
  {
    int wp0 = p0 + wid * 64;
    int nv = P - wp0;
    nv = nv < 0 ? 0 : (nv > 64 ? 64 : nv);
    int nf4 = (nv * C) >> 2;  // 336 (full), 147 (tail), or 0
    const float4* src = (const float4*)(pred_cls + ((size_t)b * P + wp0) * C);
#pragma unroll
    for (int k = 0; k < 6; k++) {
      int idx = (k << 6) + lane;
      if (idx < nf4) GLD16(src + idx, &sCls[wid][k << 8]);
    }
  }

  sinv[tid] = 0x7fffffff;
  if (tid < M) {
    int m = tid;
    float4 bx = ((const float4*)b_boxes)[b * M + m];
    sbox[m] = bx;
    sarea[m] = (bx.z - bx.x) * (bx.w - bx.y);
    slab[m] = b_labels[b * M + m];
    // fused k1_reduce: fold 8 chunk partials for object m of image b
    int o = b * M + m;
    float cI = pI[o * CH], cU = pU[o * CH];
    int ci = pidx[o * CH];
#pragma unroll
    for (int ch = 1; ch < CH; ch++) {
      float nI = pI[o * CH + ch], nU = pU[o * CH + ch];
      int ni = pidx[o * CH + ch];
      if (nI * cU > cI * nU) { cI = nI; cU = nU; ci = ni; }
    }
    sobj[m] = ci;
  }
  __syncthreads();
  if (tid < M) {
    int t = sobj[tid] - p0;
    if (t >= 0 && t < PPB) atomicMin(&sinv[t], tid);
  }
  __syncthreads();  // drains the global_load_lds vmcnt + orders sinv

  float locpart = 0.0f, cepospart = 0.0f;
  int npos = 0;
  int p = p0 + tid;
  if (p < P) {
    float4 pr = ((const float4*)priors)[p];
    float pw2 = pr.z * 0.5f, ph2 = pr.w * 0.5f;
    float px1 = pr.x - pw2, py1 = pr.y - ph2;
    float px2 = pr.x + pw2, py2 = pr.y + ph2;
    float areaP = pr.z * pr.w;
    float bI = -1.0f, bU = 1.0f;
    int bm = 0;
    for (int m = 0; m < M; m++) {
      float4 bx = sbox[m];  // one ds_read_b128 broadcast per object
      float iw = fminf(bx.z, px2) - fmaxf(bx.x, px1);
      float ih = fminf(bx.w, py2) - fmaxf(bx.y, py1);
      iw = fmaxf(iw, 0.0f);
      ih = fmaxf(ih, 0.0f);
      float inter = iw * ih;
      float uni = sarea[m] + areaP - inter;
      if (inter * bU > bI * uni) { bI = inter; bU = uni; bm = m; }
    }
    // forced best-prior override (first-max semantics preserved)
    int fm = sinv[tid];
    if (fm != 0x7fffffff) {
      if (!((bI == bU) && (bm < fm))) { bI = 1.0f; bU = 1.0f; bm = fm; }
    }
    bool pos = (2.0f * bI >= bU);  // iou >= 0.5, division-free
    int wAny = __any((int)pos);

    if (wAny) {  // wave-uniform positive path: loc load + encode + L1 loss
      float4 pl = ((const float4*)pred_loc)[(size_t)b * P + p];
      float4 bx = sbox[bm];
      float cx = (bx.x + bx.z) * 0.5f, cy = (bx.y + bx.w) * 0.5f;
      float w = bx.z - bx.x, h = bx.w - bx.y;
      float rz = __builtin_amdgcn_rcpf(pr.z);
      float rw = __builtin_amdgcn_rcpf(pr.w);
      float g0 = (cx - pr.x) * 10.0f * rz;
      float g1 = (cy - pr.y) * 10.0f * rw;
      float g2 = __logf(w * rz) * 5.0f;
      float g3 = __logf(h * rw) * 5.0f;
      if (pos) {
        locpart = fabsf(pl.x - g0) + fabsf(pl.y - g1) +
                  fabsf(pl.z - g2) + fabsf(pl.w - g3);
        npos = 1;
      }
    }

    // CE from LDS (unstabilized logsumexp; verified absmax 0.0 since R9)
    const float* u = &sCls[wid][lane * C];
    int cls = pos ? slab[bm] : 0;
    float se = 0.0f, vc = 0.0f;
#pragma unroll
    for (int c = 0; c < C; c++) {
      float x = u[c];
      se += __expf(x);
      if (c == cls) vc = x;  // predicated select, constant index
    }
    float ce = __logf(se) - vc;
    confneg[(size_t)b * P + p] = pos ? 0.0f : ce;
    cepospart = pos ? ce : 0.0f;
  }

  for (int off = 32; off >= 1; off >>= 1) {
    locpart += __shfl_down(locpart, off, 64);
    cepospart += __shfl_down(cepospart, off, 64);
    npos += __shfl_down(npos, off, 64);
  }
  __shared__ float rloc[4], rce[4];
  __shared__ int rnp[4];
  if (lane == 0) { rloc[wid] = locpart; rce[wid] = cepospart; rnp[wid] = npos; }
  __syncthreads();
  if (tid == 0) {
    int f = b * NB2 + blockIdx.x;
    ploc[f] = rloc[0] + rloc[1] + rloc[2] + rloc[3];
    pce[f] = rce[0] + rce[1] + rce[2] + rce[3];
    pnp[f] = rnp[0] + rnp[1] + rnp[2] + rnp[3];
  }
}

// ---------------- k3: per-image exact top-K + parallel finalize -------------
__global__ __launch_bounds__(1024) void k3_hardneg(
    const float* __restrict__ confneg,
    const float* __restrict__ ploc, const float* __restrict__ pce,
    const int* __restrict__ pnp,
    float* __restrict__ imgres, int* __restrict__ done,
    float* __restrict__ out) {
  int b = blockIdx.x;
  int tid = threadIdx.x;
  int wid = tid >> 6;
  int lane = tid & 63;

  __shared__ __align__(16) float s[P];
  __shared__ int histw[16 * 256];
  __shared__ __align__(16) int cnt[256];
  __shared__ int sdig, scum, sK, sLast;
  __shared__ float sLoc, sCe, sNp;
  __shared__ float rsum[16], rl[16], rc[16], rh[16], rn[16];
  __shared__ int rcnt[16];

  {
    const float4* row4 = (const float4*)(confneg + (size_t)b * P);
    for (int i = tid; i < P / 4; i += 1024) ((float4*)s)[i] = row4[i];
  }

  if (wid == 0) {  // wave 0: reduce this image's 35 per-block partials
    float lp = 0.0f, cp = 0.0f;
    int np = 0;
    if (lane < NB2) {
      int f = b * NB2 + lane;
      lp = ploc[f]; cp = pce[f]; np = pnp[f];
    }
    for (int off = 32; off >= 1; off >>= 1) {
      lp += __shfl_down(lp, off, 64);
      cp += __shfl_down(cp, off, 64);
      np += __shfl_down(np, off, 64);
    }
    if (lane == 0) {
      int K = np * 3;
      if (K > P) K = P;
      sK = K; sLoc = lp; sCe = cp; sNp = (float)np;
    }
  }
  __syncthreads();

  int K = sK;
  unsigned pfx = 0;
  int Krem = K;
#pragma unroll
  for (int pass = 3; pass >= 0; --pass) {
    int sh = pass * 8;
    for (int i = tid; i < 16 * 256; i += 1024) histw[i] = 0;
    __syncthreads();
    unsigned himask = (pass == 3) ? 0u : (0xFFFFFFFFu << (sh + 8));
    int* myh = &histw[wid * 256];
    for (int i = tid; i < P; i += 1024) {
      unsigned ub = __float_as_uint(s[i]);
      if ((ub & himask) == pfx) atomicAdd(&myh[(ub >> sh) & 255], 1);
    }
    __syncthreads();
    if (tid < 256) {
      int c = 0;
#pragma unroll
      for (int w = 0; w < 16; w++) c += histw[w * 256 + tid];
      cnt[tid] = c;
    }
    __syncthreads();
    if (wid == 0) {
      int4 c4 = ((const int4*)cnt)[lane];
      int s3 = c4.w;
      int s2 = c4.z + s3;
      int s1 = c4.y + s2;
      int s0 = c4.x + s1;
      int suf = s0;
      for (int off = 1; off < 64; off <<= 1) {
        int t = __shfl_down(suf, off, 64);
        if (lane + off < 64) suf += t;
      }
      int above = suf - s0;
      int S0 = above + s0, S1 = above + s1, S2 = above + s2, S3 = above + s3;
      int S4 = above;
      if (S3 >= Krem && S4 < Krem) { sdig = 4 * lane + 3; scum = S4; }
      else if (S2 >= Krem && S3 < Krem) { sdig = 4 * lane + 2; scum = S3; }
      else if (S1 >= Krem && S2 < Krem) { sdig = 4 * lane + 1; scum = S2; }
      else if (S0 >= Krem && S1 < Krem) { sdig = 4 * lane + 0; scum = S1; }
    }
    __syncthreads();
    pfx |= ((unsigned)sdig) << sh;
    Krem -= scum;
  }
  float tau = __uint_as_float(pfx);

  float sum = 0.0f;
  int cgt = 0;
  for (int i = tid; i < P; i += 1024) {
    float v = s[i];
    if (v > tau) { sum += v; cgt++; }
  }
  for (int off = 32; off >= 1; off >>= 1) {
    sum += __shfl_down(sum, off, 64);
    cgt += __shfl_down(cgt, off, 64);
  }
  if (lane == 0) { rsum[wid] = sum; rcnt[wid] = cgt; }
  __syncthreads();
  if (tid == 0) {
    float stot = 0.0f;
    int ctot = 0;
#pragma unroll
    for (int w = 0; w < 16; w++) { stot += rsum[w]; ctot += rcnt[w]; }
    float hard = stot + (float)(K - ctot) * tau;
    imgres[b * 4 + 0] = sLoc;
    imgres[b * 4 + 1] = sCe;
    imgres[b * 4 + 2] = hard;
    imgres[b * 4 + 3] = sNp;
    __threadfence();
    int prev = atomicAdd(done, 1);
    sLast = (prev == B - 1) ? 1 : 0;
  }
  __syncthreads();
  if (sLast) {
    __threadfence();
    float l = 0.0f, c = 0.0f, h = 0.0f, n = 0.0f;
    if (tid < B) {
      l = atomicAdd(&imgres[tid * 4 + 0], 0.0f);
      c = atomicAdd(&imgres[tid * 4 + 1], 0.0f);
      h = atomicAdd(&imgres[tid * 4 + 2], 0.0f);
      n = atomicAdd(&imgres[tid * 4 + 3], 0.0f);
    }
    for (int off = 32; off >= 1; off >>= 1) {
      l += __shfl_down(l, off, 64);
      c += __shfl_down(c, off, 64);
      h += __shfl_down(h, off, 64);
      n += __shfl_down(n, off, 64);
    }
    if (lane == 0) { rl[wid] = l; rc[wid] = c; rh[wid] = h; rn[wid] = n; }
    __syncthreads();
    if (tid == 0) {
      float L = 0, Cc = 0, H = 0, N = 0;
#pragma unroll
      for (int w = 0; w < 16; w++) { L += rl[w]; Cc += rc[w]; H += rh[w]; N += rn[w]; }
      float loc = ALPHA * L / (N * 4.0f);
      float conf = (H + Cc) / N;
      out[0] = conf + loc;
      out[1] = loc;
      out[2] = conf;
    }
  }
}

extern "C" void kernel_launch(void* const* d_in, const int* in_sizes, int n_in,
                              void* d_out, int out_size, void* d_ws, size_t ws_size,
                              hipStream_t stream) {
  (void)in_sizes; (void)n_in; (void)out_size; (void)ws_size;
  const float* pred_loc = (const float*)d_in[0];
  const float* pred_cls = (const float*)d_in[1];
  const float* b_boxes = (const float*)d_in[2];
  const int* b_labels = (const int*)d_in[3];
  const float* priors = (const float*)d_in[4];
  float* out = (float*)d_out;

  int* done = (int*)d_ws;
  float* ploc = (float*)d_ws + 8;
  float* pce = ploc + B * NB2;
  int* pnp = (int*)(pce + B * NB2);
  float* imgres = (float*)(pnp + B * NB2);
  float* pI = imgres + B * 4;
  float* pU = pI + B * M * CH;
  int* pidx = (int*)(pU + B * M * CH);
  float* confneg = (float*)(pidx + B * M * CH);

  k1_partial<<<B * CH, 256, 0, stream>>>(b_boxes, priors, pI, pU, pidx, done);
  dim3 g2(NB2, B);
  k2_perprior<<<g2, TPB2, 0, stream>>>(pred_loc, pred_cls, b_boxes, b_labels,
                                       priors, pI, pU, pidx,
                                       ploc, pce, pnp, confneg);
  k3_hardneg<<<B, 1024, 0, stream>>>(confneg, ploc, pce, pnp, imgres, done, out);
}